// Round 1
// baseline (1573.746 us; speedup 1.0000x reference)
//
#include <hip/hip_runtime.h>

// PerformerAttention: B=2, T=4096, D=1024, H=16, Dh=64, m=256, 2m=512.
// Round 0: all-fp32 (no fp32 MFMA on CDNA4 -> vector ALU). Numerics note:
// exp(-|q|^2/2) ~ 1e-14 amplifies upstream rounding by ~64x, so Q/K GEMMs
// must stay fp32-accurate; threshold is ~2% of output absmax (5.6e-8 abs).

#define TSEQ  4096
#define BSZ   2
#define BT    8192
#define DM    1024
#define NHEAD 16
#define DHEAD 64
#define FF    512   // 2m

// ---------------------------------------------------------------------------
// fp32 tiled GEMM:  C[M,N] = A[M,K] @ W[N,K]^T   (both K-major, "NT" gemm)
// 128x128 tile, BK=16, 256 threads, 8x8 microtile (rows ty*4+i / 64+ty*4+i).
// LDS stride 132 floats (528B, 16B aligned): writes 2-way, reads <=2-way.
#define GBM 128
#define GBN 128
#define GBK 16

__global__ __launch_bounds__(256, 2)
void gemm_nt_kernel(const float* __restrict__ A, const float* __restrict__ W,
                    float* __restrict__ C, int Ndim, int Kdim)
{
    __shared__ __align__(16) float As[GBK][GBM + 4];
    __shared__ __align__(16) float Bs[GBK][GBN + 4];
    const int tid = threadIdx.x;
    const int bm = blockIdx.y * GBM;
    const int bn = blockIdx.x * GBN;
    const int lr = tid >> 2;          // 0..63 : row within half-tile
    const int lc = (tid & 3) << 2;    // 0,4,8,12 : k offset
    const int ty = tid >> 4;          // 0..15
    const int tx = tid & 15;          // 0..15

    const float* Ap = A + (size_t)(bm + lr) * Kdim + lc;
    const float* Wp = W + (size_t)(bn + lr) * Kdim + lc;

    float acc[8][8] = {};

    for (int k0 = 0; k0 < Kdim; k0 += GBK) {
        const float4 a0 = *(const float4*)(Ap + k0);
        const float4 a1 = *(const float4*)(Ap + k0 + (size_t)64 * Kdim);
        const float4 b0 = *(const float4*)(Wp + k0);
        const float4 b1 = *(const float4*)(Wp + k0 + (size_t)64 * Kdim);
        __syncthreads();
        As[lc+0][lr]    = a0.x; As[lc+1][lr]    = a0.y; As[lc+2][lr]    = a0.z; As[lc+3][lr]    = a0.w;
        As[lc+0][lr+64] = a1.x; As[lc+1][lr+64] = a1.y; As[lc+2][lr+64] = a1.z; As[lc+3][lr+64] = a1.w;
        Bs[lc+0][lr]    = b0.x; Bs[lc+1][lr]    = b0.y; Bs[lc+2][lr]    = b0.z; Bs[lc+3][lr]    = b0.w;
        Bs[lc+0][lr+64] = b1.x; Bs[lc+1][lr+64] = b1.y; Bs[lc+2][lr+64] = b1.z; Bs[lc+3][lr+64] = b1.w;
        __syncthreads();
#pragma unroll
        for (int k = 0; k < GBK; ++k) {
            float av[8], bv[8];
            *(float4*)&av[0] = *(const float4*)&As[k][ty * 4];
            *(float4*)&av[4] = *(const float4*)&As[k][64 + ty * 4];
            *(float4*)&bv[0] = *(const float4*)&Bs[k][tx * 4];
            *(float4*)&bv[4] = *(const float4*)&Bs[k][64 + tx * 4];
#pragma unroll
            for (int i = 0; i < 8; ++i)
#pragma unroll
                for (int j = 0; j < 8; ++j)
                    acc[i][j] = fmaf(av[i], bv[j], acc[i][j]);
        }
    }

#pragma unroll
    for (int ih = 0; ih < 2; ++ih)
#pragma unroll
        for (int i = 0; i < 4; ++i) {
            float* Cp = C + (size_t)(bm + ih * 64 + ty * 4 + i) * Ndim + bn;
            *(float4*)(Cp + tx * 4) =
                make_float4(acc[ih*4+i][0], acc[ih*4+i][1], acc[ih*4+i][2], acc[ih*4+i][3]);
            *(float4*)(Cp + 64 + tx * 4) =
                make_float4(acc[ih*4+i][4], acc[ih*4+i][5], acc[ih*4+i][6], acc[ih*4+i][7]);
        }
}

// ---------------------------------------------------------------------------
// Kernel 2: per (bh, feature-block of 64) accumulate KV[64f][64v] and Ksum[64f]
// over T in 64-row chunks. phi computed on the fly (proj GEMM through LDS).
__global__ __launch_bounds__(256, 1)
void kv_kernel(const float* __restrict__ Kmat, const float* __restrict__ Vmat,
               const float* __restrict__ rf, float* __restrict__ KVout,
               float* __restrict__ Ksum)
{
    const int fb = blockIdx.x;        // 0..7 : feature block (0..3 cos, 4..7 sin)
    const int bh = blockIdx.y;        // 0..31
    const int b = bh >> 4, h = bh & 15;
    const int rstart = (fb & 3) << 6; // rf row offset
    const bool use_cos = (fb < 4);

    __shared__ __align__(16) float rfS[64][68];
    __shared__ __align__(16) float Kc[64][68];
    __shared__ __align__(16) float Vc[64][68];
    __shared__ __align__(16) float phiS[64][68];
    __shared__ float normS[64];

    const int tid = threadIdx.x;
    const int ty = tid >> 4, tx = tid & 15;
    const int lr = tid >> 2;          // 0..63
    const int lcq = (tid & 3) << 4;   // 0,16,32,48 : 16-float quarter of a row

    { // rf_sub[f][d], loaded once
        const float* rp = rf + (size_t)(rstart + lr) * DHEAD + lcq;
        *(float4*)&rfS[lr][lcq + 0]  = *(const float4*)(rp + 0);
        *(float4*)&rfS[lr][lcq + 4]  = *(const float4*)(rp + 4);
        *(float4*)&rfS[lr][lcq + 8]  = *(const float4*)(rp + 8);
        *(float4*)&rfS[lr][lcq + 12] = *(const float4*)(rp + 12);
    }

    float kvacc[4][4] = {};
    float ksacc[4] = {};

    const float* Kbase = Kmat + (size_t)b * TSEQ * DM + h * DHEAD;
    const float* Vbase = Vmat + (size_t)b * TSEQ * DM + h * DHEAD;

    for (int ch = 0; ch < TSEQ / 64; ++ch) {
        const float* Kp = Kbase + (size_t)(ch * 64 + lr) * DM + lcq;
        const float* Vp = Vbase + (size_t)(ch * 64 + lr) * DM + lcq;
        const float4 k0 = *(const float4*)(Kp + 0);
        const float4 k1 = *(const float4*)(Kp + 4);
        const float4 k2 = *(const float4*)(Kp + 8);
        const float4 k3 = *(const float4*)(Kp + 12);
        const float4 v0 = *(const float4*)(Vp + 0);
        const float4 v1 = *(const float4*)(Vp + 4);
        const float4 v2 = *(const float4*)(Vp + 8);
        const float4 v3 = *(const float4*)(Vp + 12);
        // row |k|^2 via shfl over the 4-lane group (avoids conflicted LDS reads)
        float nrm = k0.x*k0.x + k0.y*k0.y + k0.z*k0.z + k0.w*k0.w
                  + k1.x*k1.x + k1.y*k1.y + k1.z*k1.z + k1.w*k1.w
                  + k2.x*k2.x + k2.y*k2.y + k2.z*k2.z + k2.w*k2.w
                  + k3.x*k3.x + k3.y*k3.y + k3.z*k3.z + k3.w*k3.w;
        nrm += __shfl_xor(nrm, 1);
        nrm += __shfl_xor(nrm, 2);
        __syncthreads();   // prev chunk's KV GEMM done reading Vc/phiS
        *(float4*)&Kc[lr][lcq + 0] = k0; *(float4*)&Kc[lr][lcq + 4]  = k1;
        *(float4*)&Kc[lr][lcq + 8] = k2; *(float4*)&Kc[lr][lcq + 12] = k3;
        *(float4*)&Vc[lr][lcq + 0] = v0; *(float4*)&Vc[lr][lcq + 4]  = v1;
        *(float4*)&Vc[lr][lcq + 8] = v2; *(float4*)&Vc[lr][lcq + 12] = v3;
        if ((tid & 3) == 0) normS[lr] = nrm;
        __syncthreads();

        // proj[t=4ty+i][f=tx+16j] = sum_d Kc[t][d] * rfS[f][d]
        float pr[4][4] = {};
#pragma unroll
        for (int d0 = 0; d0 < 64; d0 += 4) {
            float ka[4][4], rb[4][4];
#pragma unroll
            for (int i = 0; i < 4; ++i) *(float4*)ka[i] = *(const float4*)&Kc[4*ty + i][d0];
#pragma unroll
            for (int j = 0; j < 4; ++j) *(float4*)rb[j] = *(const float4*)&rfS[tx + 16*j][d0];
#pragma unroll
            for (int i = 0; i < 4; ++i)
#pragma unroll
                for (int j = 0; j < 4; ++j) {
                    pr[i][j] = fmaf(ka[i][0], rb[j][0], pr[i][j]);
                    pr[i][j] = fmaf(ka[i][1], rb[j][1], pr[i][j]);
                    pr[i][j] = fmaf(ka[i][2], rb[j][2], pr[i][j]);
                    pr[i][j] = fmaf(ka[i][3], rb[j][3], pr[i][j]);
                }
        }
        float sc[4];
#pragma unroll
        for (int i = 0; i < 4; ++i) sc[i] = __expf(-0.5f * normS[4*ty + i]) * 0.0625f;
#pragma unroll
        for (int i = 0; i < 4; ++i)
#pragma unroll
            for (int j = 0; j < 4; ++j) {
                const float p = pr[i][j];
                phiS[4*ty + i][tx + 16*j] = (use_cos ? __cosf(p) : __sinf(p)) * sc[i];
            }
        __syncthreads();

        // KV[f=4ty+i][v=4tx+j] += sum_t phi[t][f] * V[t][v];  Ksum[f] += phi[t][f]
#pragma unroll 4
        for (int t = 0; t < 64; ++t) {
            float pa[4], vb[4];
            *(float4*)pa = *(const float4*)&phiS[t][4 * ty];
            *(float4*)vb = *(const float4*)&Vc[t][4 * tx];
#pragma unroll
            for (int i = 0; i < 4; ++i) {
#pragma unroll
                for (int j = 0; j < 4; ++j)
                    kvacc[i][j] = fmaf(pa[i], vb[j], kvacc[i][j]);
                ksacc[i] += pa[i];
            }
        }
    }

    float* KVp = KVout + ((size_t)bh * FF + fb * 64) * DHEAD;
#pragma unroll
    for (int i = 0; i < 4; ++i)
        *(float4*)(KVp + (size_t)(4*ty + i) * DHEAD + 4*tx) =
            make_float4(kvacc[i][0], kvacc[i][1], kvacc[i][2], kvacc[i][3]);
    if (tx == 0) {
#pragma unroll
        for (int i = 0; i < 4; ++i)
            Ksum[(size_t)bh * FF + fb * 64 + 4*ty + i] = ksacc[i];
    }
}

// ---------------------------------------------------------------------------
// Kernel 3: per (t-tile of 64, bh): Qphi on the fly, QKV = Qf@KV, Z = Qf.Ksum,
// writes Y = QKV/Z in-place over Q (block reads exactly the region it writes).
__global__ __launch_bounds__(256, 1)
void qkv_apply_kernel(const float* __restrict__ Qmat, const float* __restrict__ rf,
                      const float* __restrict__ KV, const float* __restrict__ Ksum,
                      float* __restrict__ Y)
{
    const int tt = blockIdx.x;        // 0..63
    const int bh = blockIdx.y;        // 0..31
    const int b = bh >> 4, h = bh & 15;

    __shared__ __align__(16) float Qc[64][68];
    __shared__ __align__(16) float rfS[64][68];
    __shared__ __align__(16) float phiS[64][68];
    __shared__ __align__(16) float KVs[64][68];
    __shared__ float normS[64];
    __shared__ float ksS[64];

    const int tid = threadIdx.x;
    const int ty = tid >> 4, tx = tid & 15;
    const int lr = tid >> 2;
    const int lcq = (tid & 3) << 4;

    { // load Q chunk + row norms
        const float* Qp = Qmat + (size_t)(b * TSEQ + tt * 64 + lr) * DM + h * DHEAD + lcq;
        const float4 q0 = *(const float4*)(Qp + 0);
        const float4 q1 = *(const float4*)(Qp + 4);
        const float4 q2 = *(const float4*)(Qp + 8);
        const float4 q3 = *(const float4*)(Qp + 12);
        float nrm = q0.x*q0.x + q0.y*q0.y + q0.z*q0.z + q0.w*q0.w
                  + q1.x*q1.x + q1.y*q1.y + q1.z*q1.z + q1.w*q1.w
                  + q2.x*q2.x + q2.y*q2.y + q2.z*q2.z + q2.w*q2.w
                  + q3.x*q3.x + q3.y*q3.y + q3.z*q3.z + q3.w*q3.w;
        nrm += __shfl_xor(nrm, 1);
        nrm += __shfl_xor(nrm, 2);
        *(float4*)&Qc[lr][lcq + 0]  = q0; *(float4*)&Qc[lr][lcq + 4]  = q1;
        *(float4*)&Qc[lr][lcq + 8]  = q2; *(float4*)&Qc[lr][lcq + 12] = q3;
        if ((tid & 3) == 0) normS[lr] = nrm;
    }
    __syncthreads();

    float qsc[4];
#pragma unroll
    for (int i = 0; i < 4; ++i) qsc[i] = __expf(-0.5f * normS[4*ty + i]) * 0.0625f;

    float oacc[4][4] = {};
    float zacc[4] = {};

    for (int fb = 0; fb < 8; ++fb) {
        const int rstart = (fb & 3) << 6;
        const bool use_cos = (fb < 4);
        __syncthreads();   // prev iteration done reading rfS/KVs/phiS
        {
            const float* rp = rf + (size_t)(rstart + lr) * DHEAD + lcq;
            *(float4*)&rfS[lr][lcq + 0]  = *(const float4*)(rp + 0);
            *(float4*)&rfS[lr][lcq + 4]  = *(const float4*)(rp + 4);
            *(float4*)&rfS[lr][lcq + 8]  = *(const float4*)(rp + 8);
            *(float4*)&rfS[lr][lcq + 12] = *(const float4*)(rp + 12);
            const float* kvp = KV + ((size_t)bh * FF + fb * 64 + lr) * DHEAD + lcq;
            *(float4*)&KVs[lr][lcq + 0]  = *(const float4*)(kvp + 0);
            *(float4*)&KVs[lr][lcq + 4]  = *(const float4*)(kvp + 4);
            *(float4*)&KVs[lr][lcq + 8]  = *(const float4*)(kvp + 8);
            *(float4*)&KVs[lr][lcq + 12] = *(const float4*)(kvp + 12);
            if (tid < 64) ksS[tid] = Ksum[(size_t)bh * FF + fb * 64 + tid];
        }
        __syncthreads();

        // proj GEMM (same mapping as kv_kernel)
        float pr[4][4] = {};
#pragma unroll
        for (int d0 = 0; d0 < 64; d0 += 4) {
            float qa[4][4], rb[4][4];
#pragma unroll
            for (int i = 0; i < 4; ++i) *(float4*)qa[i] = *(const float4*)&Qc[4*ty + i][d0];
#pragma unroll
            for (int j = 0; j < 4; ++j) *(float4*)rb[j] = *(const float4*)&rfS[tx + 16*j][d0];
#pragma unroll
            for (int i = 0; i < 4; ++i)
#pragma unroll
                for (int j = 0; j < 4; ++j) {
                    pr[i][j] = fmaf(qa[i][0], rb[j][0], pr[i][j]);
                    pr[i][j] = fmaf(qa[i][1], rb[j][1], pr[i][j]);
                    pr[i][j] = fmaf(qa[i][2], rb[j][2], pr[i][j]);
                    pr[i][j] = fmaf(qa[i][3], rb[j][3], pr[i][j]);
                }
        }
#pragma unroll
        for (int i = 0; i < 4; ++i)
#pragma unroll
            for (int j = 0; j < 4; ++j) {
                const float p = pr[i][j];
                phiS[4*ty + i][tx + 16*j] = (use_cos ? __cosf(p) : __sinf(p)) * qsc[i];
            }
        __syncthreads();

        // oacc[t=4ty+i][v=4tx+j] += sum_f phi[t][f]*KV[f][v];  zacc += phi*Ksum
#pragma unroll 4
        for (int f0 = 0; f0 < 64; f0 += 4) {
            float pa[4][4], kb[4][4];
#pragma unroll
            for (int i = 0; i < 4; ++i) *(float4*)pa[i] = *(const float4*)&phiS[4*ty + i][f0];
#pragma unroll
            for (int ff = 0; ff < 4; ++ff) *(float4*)kb[ff] = *(const float4*)&KVs[f0 + ff][4*tx];
#pragma unroll
            for (int i = 0; i < 4; ++i)
#pragma unroll
                for (int ff = 0; ff < 4; ++ff) {
#pragma unroll
                    for (int j = 0; j < 4; ++j)
                        oacc[i][j] = fmaf(pa[i][ff], kb[ff][j], oacc[i][j]);
                    zacc[i] = fmaf(pa[i][ff], ksS[f0 + ff], zacc[i]);
                }
        }
    }

    float* Yp = Y + (size_t)(b * TSEQ + tt * 64) * DM + h * DHEAD;
#pragma unroll
    for (int i = 0; i < 4; ++i) {
        const float inv = 1.0f / fmaxf(zacc[i], 1e-6f);
        *(float4*)(Yp + (size_t)(4*ty + i) * DM + 4*tx) =
            make_float4(oacc[i][0] * inv, oacc[i][1] * inv, oacc[i][2] * inv, oacc[i][3] * inv);
    }
}

// ---------------------------------------------------------------------------
extern "C" void kernel_launch(void* const* d_in, const int* in_sizes, int n_in,
                              void* d_out, int out_size, void* d_ws, size_t ws_size,
                              hipStream_t stream)
{
    (void)in_sizes; (void)n_in; (void)out_size; (void)ws_size;
    const float* x  = (const float*)d_in[0];
    const float* wq = (const float*)d_in[1];
    const float* wk = (const float*)d_in[2];
    const float* wv = (const float*)d_in[3];
    const float* wo = (const float*)d_in[4];
    const float* rf = (const float*)d_in[5];
    float* out = (float*)d_out;

    // workspace: Q | K | V | KV | Ksum   (~105 MB)
    float* Q  = (float*)d_ws;
    float* Kb = Q  + (size_t)BT * DM;
    float* Vb = Kb + (size_t)BT * DM;
    float* KV = Vb + (size_t)BT * DM;
    float* Ks = KV + (size_t)BSZ * NHEAD * FF * DHEAD;

    const dim3 blk(256);
    const dim3 ggrid(DM / GBN, BT / GBM);   // (8, 64)
    hipLaunchKernelGGL(gemm_nt_kernel, ggrid, blk, 0, stream, x, wq, Q,  DM, DM);
    hipLaunchKernelGGL(gemm_nt_kernel, ggrid, blk, 0, stream, x, wk, Kb, DM, DM);
    hipLaunchKernelGGL(gemm_nt_kernel, ggrid, blk, 0, stream, x, wv, Vb, DM, DM);
    hipLaunchKernelGGL(kv_kernel,       dim3(8, 32),  blk, 0, stream, Kb, Vb, rf, KV, Ks);
    hipLaunchKernelGGL(qkv_apply_kernel, dim3(64, 32), blk, 0, stream, Q, rf, KV, Ks, Q);
    hipLaunchKernelGGL(gemm_nt_kernel, ggrid, blk, 0, stream, Q, wo, out, DM, DM);
}

// Round 2
// 874.611 us; speedup vs baseline: 1.7994x; 1.7994x over previous
//
#include <hip/hip_runtime.h>

// PerformerAttention: B=2, T=4096, D=1024, H=16, Dh=64, m=256, 2m=512.
// R2: bf16 MFMA GEMMs. Q/K projections use split-bf16 (hi/lo, 3 MFMA products)
// because exp(-|q|^2/2) amplifies dq by |q|~8; norms come from the fp32 GEMM
// accumulator in the epilogue. V / out projections are plain bf16 MFMA.
// kv_kernel: 2-way T-split (512 blocks = 2 resident/CU at 70KB LDS) + reduce.

#define TSEQ  4096
#define BSZ   2
#define BT    8192
#define DM    1024
#define NHEAD 16
#define DHEAD 64
#define FF    512   // 2m

typedef __attribute__((ext_vector_type(8))) __bf16 bf16x8;
typedef __attribute__((ext_vector_type(4))) __bf16 bf16x4;
typedef __attribute__((ext_vector_type(4))) float floatx4;

#define MFMA_BF16(a, b, c) __builtin_amdgcn_mfma_f32_16x16x32_bf16(a, b, c, 0, 0, 0)

__device__ __forceinline__ void load_lds_16B(const void* g, void* l) {
    __builtin_amdgcn_global_load_lds(
        (const __attribute__((address_space(1))) void*)g,
        (__attribute__((address_space(3))) void*)l, 16, 0, 0);
}

// ---------------------------------------------------------------------------
// fp32 -> bf16 hi/lo split (lo = x - float(hi)); hi-only variant for V/O wts.
__global__ __launch_bounds__(256) void split2_kernel(
    const float* __restrict__ src, __bf16* __restrict__ hi, __bf16* __restrict__ lo, int n4)
{
    int i = blockIdx.x * 256 + threadIdx.x;
    if (i >= n4) return;
    float4 v = ((const float4*)src)[i];
    bf16x4 h = {(__bf16)v.x, (__bf16)v.y, (__bf16)v.z, (__bf16)v.w};
    bf16x4 l = {(__bf16)(v.x - (float)h[0]), (__bf16)(v.y - (float)h[1]),
                (__bf16)(v.z - (float)h[2]), (__bf16)(v.w - (float)h[3])};
    ((bf16x4*)hi)[i] = h;
    ((bf16x4*)lo)[i] = l;
}

__global__ __launch_bounds__(256) void split1_kernel(
    const float* __restrict__ src, __bf16* __restrict__ hi, int n4)
{
    int i = blockIdx.x * 256 + threadIdx.x;
    if (i >= n4) return;
    float4 v = ((const float4*)src)[i];
    bf16x4 h = {(__bf16)v.x, (__bf16)v.y, (__bf16)v.z, (__bf16)v.w};
    ((bf16x4*)hi)[i] = h;
}

// ---------------------------------------------------------------------------
// bf16 MFMA GEMM: C[M=8192, N=1024] = A @ W^T, A [M,K=1024] bf16 row-major,
// W [N,K] bf16 row-major. SPLIT: 3-product hi/lo. EPI: 0 = fp32 out,
// 1 = bf16 out, 2 = bf16 out + per-head row norms from the fp32 accumulator.
// 128x128 tile, BK=32, 4 waves; wave = 64x64 quadrant = 4x4 MFMA tiles.
template<bool SPLIT, int EPI>
__global__ __launch_bounds__(256, 2)
void gemm_mfma_kernel(const __bf16* __restrict__ Ahi, const __bf16* __restrict__ Alo,
                      const __bf16* __restrict__ Whi, const __bf16* __restrict__ Wlo,
                      float* __restrict__ Cf, __bf16* __restrict__ Cb,
                      float* __restrict__ norms)
{
    __shared__ __bf16 As[SPLIT ? 2 : 1][128 * 32];
    __shared__ __bf16 Bs[SPLIT ? 2 : 1][128 * 32];

    const int t = threadIdx.x;
    const int bm = blockIdx.y * 128, bn = blockIdx.x * 128;
    const int lane = t & 63, mth = lane & 15, q = lane >> 4, wave = t >> 6;
    const int wrow = (wave & 1) * 64, wcol = (wave >> 1) * 64;

    // staging map: thread t -> row t/4 (and +64), k-chunk (t%4)*8; LDS linear
    // offset t*16B (wave-uniform base + lane*16 as global_load_lds requires).
    const size_t arow = (size_t)(bm + (t >> 2)) * DM + ((t & 3) * 8);
    const size_t brow = (size_t)(bn + (t >> 2)) * DM + ((t & 3) * 8);
    const int l0 = t * 8;
    const int l1 = 64 * 32 + t * 8;

    floatx4 acc[4][4];
#pragma unroll
    for (int i = 0; i < 4; ++i)
#pragma unroll
        for (int j = 0; j < 4; ++j) acc[i][j] = (floatx4){0.f, 0.f, 0.f, 0.f};

    for (int k0 = 0; k0 < DM; k0 += 32) {
        __syncthreads();   // prev tile's readers done
        load_lds_16B(Ahi + arow + k0,             &As[0][l0]);
        load_lds_16B(Ahi + arow + 64 * DM + k0,   &As[0][l1]);
        load_lds_16B(Whi + brow + k0,             &Bs[0][l0]);
        load_lds_16B(Whi + brow + 64 * DM + k0,   &Bs[0][l1]);
        if (SPLIT) {
            load_lds_16B(Alo + arow + k0,           &As[1][l0]);
            load_lds_16B(Alo + arow + 64 * DM + k0, &As[1][l1]);
            load_lds_16B(Wlo + brow + k0,           &Bs[1][l0]);
            load_lds_16B(Wlo + brow + 64 * DM + k0, &Bs[1][l1]);
        }
        __syncthreads();   // staging complete (compiler drains vmcnt)

        bf16x8 ah[4], bh[4], al[4], bl[4];
#pragma unroll
        for (int i = 0; i < 4; ++i) {
            ah[i] = *(const bf16x8*)&As[0][(wrow + i * 16 + mth) * 32 + q * 8];
            bh[i] = *(const bf16x8*)&Bs[0][(wcol + i * 16 + mth) * 32 + q * 8];
        }
        if (SPLIT) {
#pragma unroll
            for (int i = 0; i < 4; ++i) {
                al[i] = *(const bf16x8*)&As[1][(wrow + i * 16 + mth) * 32 + q * 8];
                bl[i] = *(const bf16x8*)&Bs[1][(wcol + i * 16 + mth) * 32 + q * 8];
            }
        }
#pragma unroll
        for (int i = 0; i < 4; ++i)
#pragma unroll
            for (int j = 0; j < 4; ++j) {
                acc[i][j] = MFMA_BF16(ah[i], bh[j], acc[i][j]);
                if (SPLIT) {
                    acc[i][j] = MFMA_BF16(ah[i], bl[j], acc[i][j]);
                    acc[i][j] = MFMA_BF16(al[i], bh[j], acc[i][j]);
                }
            }
    }

    // epilogue: C/D layout col = lane&15, row = (lane>>4)*4 + reg
    if (EPI == 2) {
        const int head = (bn + wcol) >> 6;   // wave's 64 cols = exactly 1 head
#pragma unroll
        for (int i = 0; i < 4; ++i)
#pragma unroll
            for (int r = 0; r < 4; ++r) {
                float s = acc[i][0][r] * acc[i][0][r] + acc[i][1][r] * acc[i][1][r]
                        + acc[i][2][r] * acc[i][2][r] + acc[i][3][r] * acc[i][3][r];
                s += __shfl_xor(s, 1); s += __shfl_xor(s, 2);
                s += __shfl_xor(s, 4); s += __shfl_xor(s, 8);
                if (mth == 0)
                    norms[(size_t)(bm + wrow + i * 16 + q * 4 + r) * NHEAD + head] = s;
            }
    }
#pragma unroll
    for (int i = 0; i < 4; ++i)
#pragma unroll
        for (int r = 0; r < 4; ++r) {
            const size_t gr = (size_t)(bm + wrow + i * 16 + q * 4 + r) * DM
                            + bn + wcol + mth;
            if (EPI == 0) {
#pragma unroll
                for (int j = 0; j < 4; ++j) Cf[gr + j * 16] = acc[i][j][r];
            } else {
#pragma unroll
                for (int j = 0; j < 4; ++j) Cb[gr + j * 16] = (__bf16)acc[i][j][r];
            }
        }
}

// ---------------------------------------------------------------------------
// KV accumulation: grid (8 fb, 32 bh, 2 zsplit). Each block: 32 chunks of 64
// rows; proj GEMM through LDS, phi, KV += phi^T V, Ksum += phi.
__global__ __launch_bounds__(256, 2)
void kv_kernel(const __bf16* __restrict__ Kb, const __bf16* __restrict__ Vb,
               const float* __restrict__ Knorm, const float* __restrict__ rf,
               float* __restrict__ KVpart, float* __restrict__ KsumPart)
{
    const int fb = blockIdx.x;        // 0..7 (0..3 cos, 4..7 sin)
    const int bh = blockIdx.y;        // 0..31
    const int zs = blockIdx.z;        // 0..1
    const int b = bh >> 4, h = bh & 15;
    const int rstart = (fb & 3) << 6;
    const bool use_cos = (fb < 4);

    __shared__ __align__(16) float rfS[64][68];
    __shared__ __align__(16) float Kc[64][68];
    __shared__ __align__(16) float Vc[64][68];
    __shared__ __align__(16) float phiS[64][68];
    __shared__ float normS[64];

    const int tid = threadIdx.x;
    const int ty = tid >> 4, tx = tid & 15;
    const int lr = tid >> 2;
    const int lcq = (tid & 3) << 4;

    {
        const float* rp = rf + (size_t)(rstart + lr) * DHEAD + lcq;
        *(float4*)&rfS[lr][lcq + 0]  = *(const float4*)(rp + 0);
        *(float4*)&rfS[lr][lcq + 4]  = *(const float4*)(rp + 4);
        *(float4*)&rfS[lr][lcq + 8]  = *(const float4*)(rp + 8);
        *(float4*)&rfS[lr][lcq + 12] = *(const float4*)(rp + 12);
    }

    float kvacc[4][4] = {};
    float ksacc[4] = {};

    const __bf16* Kbase = Kb + (size_t)b * TSEQ * DM + h * DHEAD;
    const __bf16* Vbase = Vb + (size_t)b * TSEQ * DM + h * DHEAD;

    for (int ch = zs * 32; ch < zs * 32 + 32; ++ch) {
        const __bf16* Kp = Kbase + (size_t)(ch * 64 + lr) * DM + lcq;
        const __bf16* Vp = Vbase + (size_t)(ch * 64 + lr) * DM + lcq;
        const bf16x8 k0 = *(const bf16x8*)(Kp + 0);
        const bf16x8 k1 = *(const bf16x8*)(Kp + 8);
        const bf16x8 v0 = *(const bf16x8*)(Vp + 0);
        const bf16x8 v1 = *(const bf16x8*)(Vp + 8);
        __syncthreads();   // prev chunk's KV GEMM done reading Vc/phiS
#pragma unroll
        for (int e = 0; e < 8; ++e) {
            Kc[lr][lcq + e]     = (float)k0[e];
            Kc[lr][lcq + 8 + e] = (float)k1[e];
            Vc[lr][lcq + e]     = (float)v0[e];
            Vc[lr][lcq + 8 + e] = (float)v1[e];
        }
        if (tid < 64) normS[tid] = Knorm[(size_t)(b * TSEQ + ch * 64 + tid) * NHEAD + h];
        __syncthreads();

        // proj[t=4ty+i][f=tx+16j] = sum_d Kc[t][d] * rfS[f][d]
        float pr[4][4] = {};
#pragma unroll
        for (int d0 = 0; d0 < 64; d0 += 4) {
            float ka[4][4], rb[4][4];
#pragma unroll
            for (int i = 0; i < 4; ++i) *(float4*)ka[i] = *(const float4*)&Kc[4*ty + i][d0];
#pragma unroll
            for (int j = 0; j < 4; ++j) *(float4*)rb[j] = *(const float4*)&rfS[tx + 16*j][d0];
#pragma unroll
            for (int i = 0; i < 4; ++i)
#pragma unroll
                for (int j = 0; j < 4; ++j) {
                    pr[i][j] = fmaf(ka[i][0], rb[j][0], pr[i][j]);
                    pr[i][j] = fmaf(ka[i][1], rb[j][1], pr[i][j]);
                    pr[i][j] = fmaf(ka[i][2], rb[j][2], pr[i][j]);
                    pr[i][j] = fmaf(ka[i][3], rb[j][3], pr[i][j]);
                }
        }
        float sc[4];
#pragma unroll
        for (int i = 0; i < 4; ++i) sc[i] = __expf(-0.5f * normS[4*ty + i]) * 0.0625f;
#pragma unroll
        for (int i = 0; i < 4; ++i)
#pragma unroll
            for (int j = 0; j < 4; ++j) {
                const float p = pr[i][j];
                phiS[4*ty + i][tx + 16*j] = (use_cos ? __cosf(p) : __sinf(p)) * sc[i];
            }
        __syncthreads();

#pragma unroll 4
        for (int tt = 0; tt < 64; ++tt) {
            float pa[4], vb[4];
            *(float4*)pa = *(const float4*)&phiS[tt][4 * ty];
            *(float4*)vb = *(const float4*)&Vc[tt][4 * tx];
#pragma unroll
            for (int i = 0; i < 4; ++i) {
#pragma unroll
                for (int j = 0; j < 4; ++j)
                    kvacc[i][j] = fmaf(pa[i], vb[j], kvacc[i][j]);
                ksacc[i] += pa[i];
            }
        }
    }

    float* KVp = KVpart + (size_t)zs * (32 * FF * DHEAD)
               + ((size_t)bh * FF + fb * 64) * DHEAD;
#pragma unroll
    for (int i = 0; i < 4; ++i)
        *(float4*)(KVp + (size_t)(4*ty + i) * DHEAD + 4*tx) =
            make_float4(kvacc[i][0], kvacc[i][1], kvacc[i][2], kvacc[i][3]);
    if (tx == 0) {
#pragma unroll
        for (int i = 0; i < 4; ++i)
            KsumPart[(size_t)zs * (32 * FF) + (size_t)bh * FF + fb * 64 + 4*ty + i] = ksacc[i];
    }
}

#define KVN (32 * FF * DHEAD)   // 1048576
#define KSN (32 * FF)           // 16384

__global__ __launch_bounds__(256) void reduce_kv_kernel(
    const float* __restrict__ KVpart, const float* __restrict__ KsumPart,
    float* __restrict__ KV, float* __restrict__ Ksum)
{
    int i = blockIdx.x * 256 + threadIdx.x;
    if (i < KVN) KV[i] = KVpart[i] + KVpart[KVN + i];
    if (i < KSN) Ksum[i] = KsumPart[i] + KsumPart[KSN + i];
}

// ---------------------------------------------------------------------------
// Q-side: phi on the fly, QKV = Qf@KV, Z = Qf.Ksum, Y = QKV/Z -> bf16.
__global__ __launch_bounds__(256, 2)
void qkv_apply_kernel(const __bf16* __restrict__ Qb, const float* __restrict__ Qnorm,
                      const float* __restrict__ rf, const float* __restrict__ KV,
                      const float* __restrict__ Ksum, __bf16* __restrict__ Ybf)
{
    const int tt = blockIdx.x;        // 0..63
    const int bh = blockIdx.y;        // 0..31
    const int b = bh >> 4, h = bh & 15;

    __shared__ __align__(16) float Qc[64][68];
    __shared__ __align__(16) float rfS[64][68];
    __shared__ __align__(16) float phiS[64][68];
    __shared__ __align__(16) float KVs[64][68];
    __shared__ float normS[64];
    __shared__ float ksS[64];

    const int tid = threadIdx.x;
    const int ty = tid >> 4, tx = tid & 15;
    const int lr = tid >> 2;
    const int lcq = (tid & 3) << 4;

    {
        const __bf16* Qp = Qb + (size_t)(b * TSEQ + tt * 64 + lr) * DM + h * DHEAD + lcq;
        const bf16x8 q0 = *(const bf16x8*)(Qp + 0);
        const bf16x8 q1 = *(const bf16x8*)(Qp + 8);
#pragma unroll
        for (int e = 0; e < 8; ++e) {
            Qc[lr][lcq + e]     = (float)q0[e];
            Qc[lr][lcq + 8 + e] = (float)q1[e];
        }
        if (tid < 64) normS[tid] = Qnorm[(size_t)(b * TSEQ + tt * 64 + tid) * NHEAD + h];
    }
    __syncthreads();

    float qsc[4];
#pragma unroll
    for (int i = 0; i < 4; ++i) qsc[i] = __expf(-0.5f * normS[4*ty + i]) * 0.0625f;

    float oacc[4][4] = {};
    float zacc[4] = {};

    for (int fb = 0; fb < 8; ++fb) {
        const int rstart = (fb & 3) << 6;
        const bool use_cos = (fb < 4);
        __syncthreads();
        {
            const float* rp = rf + (size_t)(rstart + lr) * DHEAD + lcq;
            *(float4*)&rfS[lr][lcq + 0]  = *(const float4*)(rp + 0);
            *(float4*)&rfS[lr][lcq + 4]  = *(const float4*)(rp + 4);
            *(float4*)&rfS[lr][lcq + 8]  = *(const float4*)(rp + 8);
            *(float4*)&rfS[lr][lcq + 12] = *(const float4*)(rp + 12);
            const float* kvp = KV + ((size_t)bh * FF + fb * 64 + lr) * DHEAD + lcq;
            *(float4*)&KVs[lr][lcq + 0]  = *(const float4*)(kvp + 0);
            *(float4*)&KVs[lr][lcq + 4]  = *(const float4*)(kvp + 4);
            *(float4*)&KVs[lr][lcq + 8]  = *(const float4*)(kvp + 8);
            *(float4*)&KVs[lr][lcq + 12] = *(const float4*)(kvp + 12);
            if (tid < 64) ksS[tid] = Ksum[(size_t)bh * FF + fb * 64 + tid];
        }
        __syncthreads();

        float pr[4][4] = {};
#pragma unroll
        for (int d0 = 0; d0 < 64; d0 += 4) {
            float qa[4][4], rb[4][4];
#pragma unroll
            for (int i = 0; i < 4; ++i) *(float4*)qa[i] = *(const float4*)&Qc[4*ty + i][d0];
#pragma unroll
            for (int j = 0; j < 4; ++j) *(float4*)rb[j] = *(const float4*)&rfS[tx + 16*j][d0];
#pragma unroll
            for (int i = 0; i < 4; ++i)
#pragma unroll
                for (int j = 0; j < 4; ++j) {
                    pr[i][j] = fmaf(qa[i][0], rb[j][0], pr[i][j]);
                    pr[i][j] = fmaf(qa[i][1], rb[j][1], pr[i][j]);
                    pr[i][j] = fmaf(qa[i][2], rb[j][2], pr[i][j]);
                    pr[i][j] = fmaf(qa[i][3], rb[j][3], pr[i][j]);
                }
        }
#pragma unroll
        for (int i = 0; i < 4; ++i)
#pragma unroll
            for (int j = 0; j < 4; ++j) {
                const float p = pr[i][j];
                phiS[4*ty + i][tx + 16*j] = (use_cos ? __cosf(p) : __sinf(p)) * qsc[i];
            }
        __syncthreads();

#pragma unroll 4
        for (int f0 = 0; f0 < 64; f0 += 4) {
            float pa[4][4], kb[4][4];
#pragma unroll
            for (int i = 0; i < 4; ++i) *(float4*)pa[i] = *(const float4*)&phiS[4*ty + i][f0];
#pragma unroll
            for (int ff = 0; ff < 4; ++ff) *(float4*)kb[ff] = *(const float4*)&KVs[f0 + ff][4*tx];
#pragma unroll
            for (int i = 0; i < 4; ++i)
#pragma unroll
                for (int ff = 0; ff < 4; ++ff) {
#pragma unroll
                    for (int j = 0; j < 4; ++j)
                        oacc[i][j] = fmaf(pa[i][ff], kb[ff][j], oacc[i][j]);
                    zacc[i] = fmaf(pa[i][ff], ksS[f0 + ff], zacc[i]);
                }
        }
    }

    __bf16* Yp = Ybf + (size_t)(b * TSEQ + tt * 64) * DM + h * DHEAD;
#pragma unroll
    for (int i = 0; i < 4; ++i) {
        const float inv = 1.0f / fmaxf(zacc[i], 1e-6f);
        bf16x4 w = {(__bf16)(oacc[i][0] * inv), (__bf16)(oacc[i][1] * inv),
                    (__bf16)(oacc[i][2] * inv), (__bf16)(oacc[i][3] * inv)};
        *(bf16x4*)(Yp + (size_t)(4*ty + i) * DM + 4*tx) = w;
    }
}

// ---------------------------------------------------------------------------
extern "C" void kernel_launch(void* const* d_in, const int* in_sizes, int n_in,
                              void* d_out, int out_size, void* d_ws, size_t ws_size,
                              hipStream_t stream)
{
    (void)in_sizes; (void)n_in; (void)out_size; (void)ws_size;
    const float* x  = (const float*)d_in[0];
    const float* wq = (const float*)d_in[1];
    const float* wk = (const float*)d_in[2];
    const float* wv = (const float*)d_in[3];
    const float* wo = (const float*)d_in[4];
    const float* rf = (const float*)d_in[5];
    float* out = (float*)d_out;

    const size_t MN = (size_t)BT * DM;     // 8388608
    const size_t WN = (size_t)DM * DM;     // 1048576

    // workspace layout (~102 MB), with phase-overlay reuse:
    __bf16* Qb   = (__bf16*)d_ws;          // MN
    __bf16* Kb   = Qb  + MN;               // MN
    __bf16* Vb   = Kb  + MN;               // MN
    __bf16* Xhi  = Vb  + MN;               // MN  (reused as Ybf after V gemm)
    __bf16* Xlo  = Xhi + MN;               // MN  (reused as KVpart after K gemm)
    __bf16* Wqh  = Xlo + MN;               // WN each
    __bf16* Wql  = Wqh + WN;
    __bf16* Wkh  = Wql + WN;
    __bf16* Wkl  = Wkh + WN;
    __bf16* Wvh  = Wkl + WN;
    __bf16* Woh  = Wvh + WN;
    float* Qnorm = (float*)(Woh + WN);     // BT*16
    float* Knorm = Qnorm + (size_t)BT * NHEAD;
    float* KV    = Knorm + (size_t)BT * NHEAD;   // KVN
    float* Ksum  = KV + KVN;                     // KSN
    float* KVpart  = (float*)Xlo;          // 2*KVN floats = 8.4MB <= 16.8MB
    float* KsumP   = KVpart + 2 * KVN;
    __bf16* Ybf  = Xhi;

    const dim3 blk(256);
    // splits
    hipLaunchKernelGGL(split2_kernel, dim3(MN / 4 / 256), blk, 0, stream, x,  Xhi, Xlo, (int)(MN / 4));
    hipLaunchKernelGGL(split2_kernel, dim3(WN / 4 / 256), blk, 0, stream, wq, Wqh, Wql, (int)(WN / 4));
    hipLaunchKernelGGL(split2_kernel, dim3(WN / 4 / 256), blk, 0, stream, wk, Wkh, Wkl, (int)(WN / 4));
    hipLaunchKernelGGL(split1_kernel, dim3(WN / 4 / 256), blk, 0, stream, wv, Wvh, (int)(WN / 4));
    hipLaunchKernelGGL(split1_kernel, dim3(WN / 4 / 256), blk, 0, stream, wo, Woh, (int)(WN / 4));

    const dim3 ggrid(DM / 128, BT / 128);  // (8, 64)
    // Q, K: split-bf16 3-product, epilogue bf16 + norms
    hipLaunchKernelGGL((gemm_mfma_kernel<true, 2>), ggrid, blk, 0, stream,
                       Xhi, Xlo, Wqh, Wql, (float*)nullptr, Qb, Qnorm);
    hipLaunchKernelGGL((gemm_mfma_kernel<true, 2>), ggrid, blk, 0, stream,
                       Xhi, Xlo, Wkh, Wkl, (float*)nullptr, Kb, Knorm);
    // V: plain bf16
    hipLaunchKernelGGL((gemm_mfma_kernel<false, 1>), ggrid, blk, 0, stream,
                       Xhi, (const __bf16*)nullptr, Wvh, (const __bf16*)nullptr,
                       (float*)nullptr, Vb, (float*)nullptr);
    // KV accumulation (2-way T-split) + reduce
    hipLaunchKernelGGL(kv_kernel, dim3(8, 32, 2), blk, 0, stream, Kb, Vb, Knorm, rf, KVpart, KsumP);
    hipLaunchKernelGGL(reduce_kv_kernel, dim3(KVN / 256), blk, 0, stream, KVpart, KsumP, KV, Ksum);
    // Q-side apply -> Ybf (overwrites Xhi region; V gemm already done)
    hipLaunchKernelGGL(qkv_apply_kernel, dim3(64, 32), blk, 0, stream, Qb, Qnorm, rf, KV, Ksum, Ybf);
    // out = Y @ wo^T, fp32 out
    hipLaunchKernelGGL((gemm_mfma_kernel<false, 0>), ggrid, blk, 0, stream,
                       Ybf, (const __bf16*)nullptr, Woh, (const __bf16*)nullptr,
                       out, (__bf16*)nullptr, (float*)nullptr);
}

// Round 3
// 413.798 us; speedup vs baseline: 3.8032x; 2.1136x over previous
//
#include <hip/hip_runtime.h>

// PerformerAttention: B=2, T=4096, D=1024, H=16, Dh=64, m=256, 2m=512.
// R3: MFMA everywhere. All four attention GEMMs are NT-form mfma(X,Y):
// D[r][c] = sum_k X[r][k]*Y[c][k], D layout col=lane&15, row=quad*4+reg.
//   kv : proj[t][f]=K.rf (pack t -> phiT), KV[f][v]=phiT.Vt (V pre-transposed)
//   qkv: projT[f][t]=rf.Q (pack f -> phi),  OT[v][t]=KVt.phi (Z = KVt row 64)
// Precision: rf, KVt split hi/lo; k-side phi split; q-side phi plain bf16.

#define TSEQ  4096
#define BSZ   2
#define BT    8192
#define DM    1024
#define NHEAD 16
#define DHEAD 64
#define FF    512   // 2m

typedef __attribute__((ext_vector_type(8))) __bf16 bf16x8;
typedef __attribute__((ext_vector_type(4))) __bf16 bf16x4;
typedef __attribute__((ext_vector_type(4))) float floatx4;

#define MFMA_BF16(a, b, c) __builtin_amdgcn_mfma_f32_16x16x32_bf16(a, b, c, 0, 0, 0)

__device__ __forceinline__ void load_lds_16B(const void* g, void* l) {
    __builtin_amdgcn_global_load_lds(
        (const __attribute__((address_space(1))) void*)g,
        (__attribute__((address_space(3))) void*)l, 16, 0, 0);
}

// ---------------------------------------------------------------------------
__global__ __launch_bounds__(256) void split2_kernel(
    const float* __restrict__ src, __bf16* __restrict__ hi, __bf16* __restrict__ lo, int n4)
{
    int i = blockIdx.x * 256 + threadIdx.x;
    if (i >= n4) return;
    float4 v = ((const float4*)src)[i];
    bf16x4 h = {(__bf16)v.x, (__bf16)v.y, (__bf16)v.z, (__bf16)v.w};
    bf16x4 l = {(__bf16)(v.x - (float)h[0]), (__bf16)(v.y - (float)h[1]),
                (__bf16)(v.z - (float)h[2]), (__bf16)(v.w - (float)h[3])};
    ((bf16x4*)hi)[i] = h;
    ((bf16x4*)lo)[i] = l;
}

__global__ __launch_bounds__(256) void split1_kernel(
    const float* __restrict__ src, __bf16* __restrict__ hi, int n4)
{
    int i = blockIdx.x * 256 + threadIdx.x;
    if (i >= n4) return;
    float4 v = ((const float4*)src)[i];
    bf16x4 h = {(__bf16)v.x, (__bf16)v.y, (__bf16)v.z, (__bf16)v.w};
    ((bf16x4*)hi)[i] = h;
}

// ---------------------------------------------------------------------------
// bf16 MFMA GEMM: C[8192,1024] = A @ W^T. SPLIT: 3-product hi/lo.
// EPI: 0 fp32 C; 1 bf16 C; 2 bf16 C + per-head row norms; 3 transposed-bf16
// (Vt layout [bh][64 v][4096 t]) via Cb.
template<bool SPLIT, int EPI>
__global__ __launch_bounds__(256, 2)
void gemm_mfma_kernel(const __bf16* __restrict__ Ahi, const __bf16* __restrict__ Alo,
                      const __bf16* __restrict__ Whi, const __bf16* __restrict__ Wlo,
                      float* __restrict__ Cf, __bf16* __restrict__ Cb,
                      float* __restrict__ norms)
{
    __shared__ __bf16 As[SPLIT ? 2 : 1][128 * 32];
    __shared__ __bf16 Bs[SPLIT ? 2 : 1][128 * 32];

    const int t = threadIdx.x;
    const int bm = blockIdx.y * 128, bn = blockIdx.x * 128;
    const int lane = t & 63, mth = lane & 15, q = lane >> 4, wave = t >> 6;
    const int wrow = (wave & 1) * 64, wcol = (wave >> 1) * 64;

    const size_t arow = (size_t)(bm + (t >> 2)) * DM + ((t & 3) * 8);
    const size_t brow = (size_t)(bn + (t >> 2)) * DM + ((t & 3) * 8);
    const int l0 = t * 8;
    const int l1 = 64 * 32 + t * 8;

    floatx4 acc[4][4];
#pragma unroll
    for (int i = 0; i < 4; ++i)
#pragma unroll
        for (int j = 0; j < 4; ++j) acc[i][j] = (floatx4){0.f, 0.f, 0.f, 0.f};

    for (int k0 = 0; k0 < DM; k0 += 32) {
        __syncthreads();
        load_lds_16B(Ahi + arow + k0,             &As[0][l0]);
        load_lds_16B(Ahi + arow + 64 * DM + k0,   &As[0][l1]);
        load_lds_16B(Whi + brow + k0,             &Bs[0][l0]);
        load_lds_16B(Whi + brow + 64 * DM + k0,   &Bs[0][l1]);
        if (SPLIT) {
            load_lds_16B(Alo + arow + k0,           &As[1][l0]);
            load_lds_16B(Alo + arow + 64 * DM + k0, &As[1][l1]);
            load_lds_16B(Wlo + brow + k0,           &Bs[1][l0]);
            load_lds_16B(Wlo + brow + 64 * DM + k0, &Bs[1][l1]);
        }
        __syncthreads();

        bf16x8 ah[4], bh[4], al[4], bl[4];
#pragma unroll
        for (int i = 0; i < 4; ++i) {
            ah[i] = *(const bf16x8*)&As[0][(wrow + i * 16 + mth) * 32 + q * 8];
            bh[i] = *(const bf16x8*)&Bs[0][(wcol + i * 16 + mth) * 32 + q * 8];
        }
        if (SPLIT) {
#pragma unroll
            for (int i = 0; i < 4; ++i) {
                al[i] = *(const bf16x8*)&As[1][(wrow + i * 16 + mth) * 32 + q * 8];
                bl[i] = *(const bf16x8*)&Bs[1][(wcol + i * 16 + mth) * 32 + q * 8];
            }
        }
#pragma unroll
        for (int i = 0; i < 4; ++i)
#pragma unroll
            for (int j = 0; j < 4; ++j) {
                acc[i][j] = MFMA_BF16(ah[i], bh[j], acc[i][j]);
                if (SPLIT) {
                    acc[i][j] = MFMA_BF16(ah[i], bl[j], acc[i][j]);
                    acc[i][j] = MFMA_BF16(al[i], bh[j], acc[i][j]);
                }
            }
    }

    if (EPI == 2) {
        const int head = (bn + wcol) >> 6;
#pragma unroll
        for (int i = 0; i < 4; ++i)
#pragma unroll
            for (int r = 0; r < 4; ++r) {
                float s = acc[i][0][r] * acc[i][0][r] + acc[i][1][r] * acc[i][1][r]
                        + acc[i][2][r] * acc[i][2][r] + acc[i][3][r] * acc[i][3][r];
                s += __shfl_xor(s, 1); s += __shfl_xor(s, 2);
                s += __shfl_xor(s, 4); s += __shfl_xor(s, 8);
                if (mth == 0)
                    norms[(size_t)(bm + wrow + i * 16 + q * 4 + r) * NHEAD + head] = s;
            }
    }
    if (EPI == 3) {
        // transposed write: Vt[(b*16+h)*64 + vloc][4096] ; regs pack along t
#pragma unroll
        for (int i = 0; i < 4; ++i)
#pragma unroll
            for (int j = 0; j < 4; ++j) {
                const int cg = bn + wcol + j * 16 + mth;
                const int hh = cg >> 6, vloc = cg & 63;
                const int r0 = bm + wrow + i * 16 + q * 4;
                const int bb = r0 >> 12, tloc = r0 & 4095;
                bf16x4 w = {(__bf16)acc[i][j][0], (__bf16)acc[i][j][1],
                            (__bf16)acc[i][j][2], (__bf16)acc[i][j][3]};
                *(bf16x4*)(Cb + ((size_t)(bb * 16 + hh) * 64 + vloc) * TSEQ + tloc) = w;
            }
        return;
    }
#pragma unroll
    for (int i = 0; i < 4; ++i)
#pragma unroll
        for (int r = 0; r < 4; ++r) {
            const size_t gr = (size_t)(bm + wrow + i * 16 + q * 4 + r) * DM
                            + bn + wcol + mth;
            if (EPI == 0) {
#pragma unroll
                for (int j = 0; j < 4; ++j) Cf[gr + j * 16] = acc[i][j][r];
            } else {
#pragma unroll
                for (int j = 0; j < 4; ++j) Cb[gr + j * 16] = (__bf16)acc[i][j][r];
            }
        }
}

// ---------------------------------------------------------------------------
// kv: grid (4 fb, 32 bh, 4 z). Per chunk of 64 t: proj MFMA -> phi (split) ->
// KV MFMA into acc[2 strips][5 vtiles]. Vt ones-col (v=64) yields Ksum.
__global__ __launch_bounds__(256, 2)
void kv_mfma_kernel(const __bf16* __restrict__ Kb, const __bf16* __restrict__ Vt,
                    const float* __restrict__ Knorm,
                    const __bf16* __restrict__ rfh_g, const __bf16* __restrict__ rfl_g,
                    float* __restrict__ KVpart)
{
    __shared__ __bf16 rfh[4096], rfl[4096], Kc[4096], VtS[5120];
    __shared__ __bf16 phiH[8192], phiL[8192];
    __shared__ float scaleS[64];

    const int fb = blockIdx.x, bh = blockIdx.y, z = blockIdx.z;
    const int b = bh >> 4, h = bh & 15;
    const int tid = threadIdx.x, wave = tid >> 6, lane = tid & 63;
    const int m = lane & 15, q = lane >> 4;
    const int lr = lane >> 2, lc8 = (lane & 3) * 8;

    // rf staged once: L = kt, wave = fblk
#pragma unroll
    for (int L = 0; L < 2; ++L) {
        const int f = wave * 16 + lr, d = L * 32 + lc8;
        load_lds_16B(rfh_g + (size_t)(fb * 64 + f) * DHEAD + d,
                     (char*)rfh + L * 4096 + wave * 1024 + lane * 16);
        load_lds_16B(rfl_g + (size_t)(fb * 64 + f) * DHEAD + d,
                     (char*)rfl + L * 4096 + wave * 1024 + lane * 16);
    }
    // ones rows v=64..79 (constant across chunks)
    for (int idx = tid; idx < 1024; idx += 256) {
        const int kt = idx >> 9, rr = (idx >> 5) & 15, c = idx & 31;
        VtS[kt * 2560 + (64 + rr) * 32 + c] = (rr == 0) ? (__bf16)1.0f : (__bf16)0.0f;
    }

    floatx4 acc[2][5];
#pragma unroll
    for (int s = 0; s < 2; ++s)
#pragma unroll
        for (int v = 0; v < 5; ++v) acc[s][v] = (floatx4){0.f, 0.f, 0.f, 0.f};

    for (int ch = z * 16; ch < z * 16 + 16; ++ch) {
        __syncthreads();
#pragma unroll
        for (int L = 0; L < 2; ++L) {
            const int tr = wave * 16 + lr, d = L * 32 + lc8;
            load_lds_16B(Kb + (size_t)(b * TSEQ + ch * 64 + tr) * DM + h * 64 + d,
                         (char*)Kc + L * 4096 + wave * 1024 + lane * 16);
            load_lds_16B(Vt + ((size_t)bh * 64 + tr) * TSEQ + ch * 64 + d,
                         (char*)VtS + L * 5120 + wave * 1024 + lane * 16);
        }
        if (tid < 64)
            scaleS[tid] = __expf(-0.5f * Knorm[(size_t)(b * TSEQ + ch * 64 + tid) * NHEAD + h]) * 0.0625f;
        __syncthreads();

        // proj[t][f]: X = K rows (wave strip), Y = rf rows
        floatx4 pr[4];
#pragma unroll
        for (int ft = 0; ft < 4; ++ft) pr[ft] = (floatx4){0.f, 0.f, 0.f, 0.f};
#pragma unroll
        for (int kt = 0; kt < 2; ++kt) {
            const bf16x8 ka = *(const bf16x8*)(Kc + kt * 2048 + (wave * 16 + m) * 32 + q * 8);
#pragma unroll
            for (int ft = 0; ft < 4; ++ft) {
                const bf16x8 yh = *(const bf16x8*)(rfh + kt * 2048 + (ft * 16 + m) * 32 + q * 8);
                const bf16x8 yl = *(const bf16x8*)(rfl + kt * 2048 + (ft * 16 + m) * 32 + q * 8);
                pr[ft] = MFMA_BF16(ka, yh, pr[ft]);
                pr[ft] = MFMA_BF16(ka, yl, pr[ft]);
            }
        }
        // phi (split) -> phiT[fo][t], b64-packed along t
#pragma unroll
        for (int ft = 0; ft < 4; ++ft) {
            const int fo = ft * 16 + m;
            bf16x4 ch_, cl_, sh_, sl_;
#pragma unroll
            for (int r = 0; r < 4; ++r) {
                const float sc = scaleS[wave * 16 + q * 4 + r];
                const float p = pr[ft][r];
                const float c = __cosf(p) * sc, s = __sinf(p) * sc;
                const __bf16 chh = (__bf16)c, shh = (__bf16)s;
                ch_[r] = chh; cl_[r] = (__bf16)(c - (float)chh);
                sh_[r] = shh; sl_[r] = (__bf16)(s - (float)shh);
            }
            const int off = (wave >> 1) * 4096 + fo * 32 + (wave & 1) * 16 + q * 4;
            *(bf16x4*)(phiH + off) = ch_;
            *(bf16x4*)(phiL + off) = cl_;
            *(bf16x4*)(phiH + off + 2048) = sh_;   // sin rows fo+64
            *(bf16x4*)(phiL + off + 2048) = sl_;
        }
        __syncthreads();

        // KV[fo][v]: X = phiT rows (2 strips/wave), Y = Vt rows
#pragma unroll
        for (int kt = 0; kt < 2; ++kt) {
            bf16x8 vv[5];
#pragma unroll
            for (int vt = 0; vt < 5; ++vt)
                vv[vt] = *(const bf16x8*)(VtS + kt * 2560 + (vt * 16 + m) * 32 + q * 8);
#pragma unroll
            for (int st = 0; st < 2; ++st) {
                const int fo = st * 64 + wave * 16 + m;
                const bf16x8 ph = *(const bf16x8*)(phiH + kt * 4096 + fo * 32 + q * 8);
                const bf16x8 pl = *(const bf16x8*)(phiL + kt * 4096 + fo * 32 + q * 8);
#pragma unroll
                for (int vt = 0; vt < 5; ++vt) {
                    acc[st][vt] = MFMA_BF16(ph, vv[vt], acc[st][vt]);
                    acc[st][vt] = MFMA_BF16(pl, vv[vt], acc[st][vt]);
                }
            }
        }
    }

    // KVpart[z][bh][v 80][f 512] fp32; regs pack along f
#pragma unroll
    for (int st = 0; st < 2; ++st)
#pragma unroll
        for (int vt = 0; vt < 5; ++vt) {
            const int v = vt * 16 + m;
            const int fo0 = st * 64 + wave * 16 + q * 4;
            const int fg0 = (fo0 < 64) ? fb * 64 + fo0 : 256 + fb * 64 + (fo0 - 64);
            *(floatx4*)(KVpart + (((size_t)z * 32 + bh) * 80 + v) * 512 + fg0) = acc[st][vt];
        }
}

#define KVTN (32 * 80 * 512)   // 1310720

__global__ __launch_bounds__(256) void reduce_kv_kernel(
    const float* __restrict__ KVpart, __bf16* __restrict__ KVthi, __bf16* __restrict__ KVtlo)
{
    const int i = blockIdx.x * 256 + threadIdx.x;   // float4 index, < KVTN/4
    const float4* P = (const float4*)KVpart;
    float4 s = P[i];
    const float4 s1 = P[i + KVTN / 4], s2 = P[i + 2 * KVTN / 4], s3 = P[i + 3 * KVTN / 4];
    s.x += s1.x + s2.x + s3.x; s.y += s1.y + s2.y + s3.y;
    s.z += s1.z + s2.z + s3.z; s.w += s1.w + s2.w + s3.w;
    bf16x4 h = {(__bf16)s.x, (__bf16)s.y, (__bf16)s.z, (__bf16)s.w};
    bf16x4 l = {(__bf16)(s.x - (float)h[0]), (__bf16)(s.y - (float)h[1]),
                (__bf16)(s.z - (float)h[2]), (__bf16)(s.w - (float)h[3])};
    ((bf16x4*)KVthi)[i] = h;
    ((bf16x4*)KVtlo)[i] = l;
}

// ---------------------------------------------------------------------------
// qkv: grid (32 tt, 32 bh), t-tile 128 (2 subs of 64). Per fb: stage KVt
// slice; per sub: projT[f][t] = rf.Q -> phi[t][f] (over rf region) ->
// OT[v][t] += KVt.phi. Z = OT row v=64.
__global__ __launch_bounds__(256, 2)
void qkv_mfma_kernel(const __bf16* __restrict__ Qb, const float* __restrict__ Qnorm,
                     const __bf16* __restrict__ rfh_g, const __bf16* __restrict__ rfl_g,
                     const __bf16* __restrict__ KVthi, const __bf16* __restrict__ KVtlo,
                     __bf16* __restrict__ Ybf)
{
    __shared__ __bf16 Qs[4096], uS[8192], KVh[10240], KVl[10240];
    __shared__ float scaleS[128];

    const int tt = blockIdx.x, bh = blockIdx.y;
    const int b = bh >> 4, h = bh & 15;
    const int t0 = tt * 128;
    const int tid = threadIdx.x, wave = tid >> 6, lane = tid & 63;
    const int m = lane & 15, q = lane >> 4;
    const int lr = lane >> 2, lc8 = (lane & 3) * 8;

    if (tid < 128)
        scaleS[tid] = __expf(-0.5f * Qnorm[(size_t)(b * TSEQ + t0 + tid) * NHEAD + h]) * 0.0625f;

    floatx4 acc[2][5];
#pragma unroll
    for (int s = 0; s < 2; ++s)
#pragma unroll
        for (int v = 0; v < 5; ++v) acc[s][v] = (floatx4){0.f, 0.f, 0.f, 0.f};

    for (int fb = 0; fb < 4; ++fb) {
        __syncthreads();   // prev fb's O-MFMA done with KVh/KVl
        // stage KVt slice: [4 ktf][80 v][32 f'] hi+lo ; ktf = wave, vblk = L%5
#pragma unroll
        for (int L = 0; L < 10; ++L) {
            const int vblk = L % 5;
            const int v = vblk * 16 + lr;
            const int fg = (wave < 2) ? fb * 64 + wave * 32 + lc8
                                      : 256 + fb * 64 + (wave - 2) * 32 + lc8;
            const __bf16* g = (L < 5 ? KVthi : KVtlo) + ((size_t)bh * 80 + v) * 512 + fg;
            load_lds_16B(g, (char*)(L < 5 ? KVh : KVl) + wave * 5120 + vblk * 1024 + lane * 16);
        }
        for (int sub = 0; sub < 2; ++sub) {
            __syncthreads();   // prev phi/Qs readers done; drains KVt stage too
#pragma unroll
            for (int L = 0; L < 2; ++L) {
                const int tr = wave * 16 + lr, d = L * 32 + lc8;
                load_lds_16B(Qb + (size_t)(b * TSEQ + t0 + sub * 64 + tr) * DM + h * 64 + d,
                             (char*)Qs + L * 4096 + wave * 1024 + lane * 16);
                load_lds_16B(rfh_g + (size_t)(fb * 64 + tr) * DHEAD + d,
                             (char*)uS + L * 4096 + wave * 1024 + lane * 16);
                load_lds_16B(rfl_g + (size_t)(fb * 64 + tr) * DHEAD + d,
                             (char*)uS + 8192 + L * 4096 + wave * 1024 + lane * 16);
            }
            __syncthreads();
            // projT[f][t]: X = rf strip (wave), Y = Q t-tiles
            floatx4 pr[4];
#pragma unroll
            for (int i = 0; i < 4; ++i) pr[i] = (floatx4){0.f, 0.f, 0.f, 0.f};
#pragma unroll
            for (int kt = 0; kt < 2; ++kt) {
                const bf16x8 xh = *(const bf16x8*)(uS + kt * 2048 + (wave * 16 + m) * 32 + q * 8);
                const bf16x8 xl = *(const bf16x8*)(uS + 4096 + kt * 2048 + (wave * 16 + m) * 32 + q * 8);
#pragma unroll
                for (int tt_ = 0; tt_ < 4; ++tt_) {
                    const bf16x8 yq = *(const bf16x8*)(Qs + kt * 2048 + (tt_ * 16 + m) * 32 + q * 8);
                    pr[tt_] = MFMA_BF16(xh, yq, pr[tt_]);
                    pr[tt_] = MFMA_BF16(xl, yq, pr[tt_]);
                }
            }
            __syncthreads();   // proj reads of uS done -> phi overwrites uS
            // phi[t][f'] b64-packed along f (regs = f-consecutive)
#pragma unroll
            for (int tt_ = 0; tt_ < 4; ++tt_) {
                const int tloc = tt_ * 16 + m;
                const float sc = scaleS[sub * 64 + tloc];
                bf16x4 pc, ps;
#pragma unroll
                for (int r = 0; r < 4; ++r) {
                    const float p = pr[tt_][r];
                    pc[r] = (__bf16)(__cosf(p) * sc);
                    ps[r] = (__bf16)(__sinf(p) * sc);
                }
                const int off = (wave >> 1) * 2048 + tloc * 32 + (wave & 1) * 16 + q * 4;
                *(bf16x4*)(uS + off) = pc;          // cos: ktf 0..1
                *(bf16x4*)(uS + 4096 + off) = ps;   // sin: ktf 2..3
            }
            __syncthreads();
            // OT[v][t]: X = KVt rows, Y = phi rows (wave = t-tile)
#pragma unroll
            for (int ktf = 0; ktf < 4; ++ktf) {
                const bf16x8 yf = *(const bf16x8*)(uS + ktf * 2048 + (wave * 16 + m) * 32 + q * 8);
#pragma unroll
                for (int vt = 0; vt < 5; ++vt) {
                    const bf16x8 xh = *(const bf16x8*)(KVh + ktf * 2560 + (vt * 16 + m) * 32 + q * 8);
                    const bf16x8 xl = *(const bf16x8*)(KVl + ktf * 2560 + (vt * 16 + m) * 32 + q * 8);
                    acc[sub][vt] = MFMA_BF16(xh, yf, acc[sub][vt]);
                    acc[sub][vt] = MFMA_BF16(xl, yf, acc[sub][vt]);
                }
            }
        }
    }
    // epilogue: Z at (vt=4, q=0, r=0), col t = m
#pragma unroll
    for (int sub = 0; sub < 2; ++sub) {
        const float z = __shfl(acc[sub][4][0], m);
        const float inv = 1.0f / fmaxf(z, 1e-6f);
        const size_t tg = (size_t)(b * TSEQ + t0 + sub * 64 + wave * 16 + m);
#pragma unroll
        for (int vt = 0; vt < 4; ++vt) {
            bf16x4 w;
#pragma unroll
            for (int r = 0; r < 4; ++r) w[r] = (__bf16)(acc[sub][vt][r] * inv);
            *(bf16x4*)(Ybf + tg * DM + h * 64 + vt * 16 + q * 4) = w;
        }
    }
}

// ---------------------------------------------------------------------------
extern "C" void kernel_launch(void* const* d_in, const int* in_sizes, int n_in,
                              void* d_out, int out_size, void* d_ws, size_t ws_size,
                              hipStream_t stream)
{
    (void)in_sizes; (void)n_in; (void)out_size; (void)ws_size;
    const float* x  = (const float*)d_in[0];
    const float* wq = (const float*)d_in[1];
    const float* wk = (const float*)d_in[2];
    const float* wv = (const float*)d_in[3];
    const float* wo = (const float*)d_in[4];
    const float* rf = (const float*)d_in[5];
    float* out = (float*)d_out;

    const size_t MN = (size_t)BT * DM;     // 8388608
    const size_t WN = (size_t)DM * DM;     // 1048576
    const size_t RN = 256 * 64;            // 16384

    __bf16* Qb    = (__bf16*)d_ws;         // MN
    __bf16* Kbf   = Qb   + MN;             // MN
    __bf16* Vtb   = Kbf  + MN;             // MN  ([bh][64][4096])
    __bf16* Xhi   = Vtb  + MN;             // MN
    __bf16* Xlo   = Xhi  + MN;             // MN
    __bf16* Wqh   = Xlo  + MN;
    __bf16* Wql   = Wqh + WN;
    __bf16* Wkh   = Wql + WN;
    __bf16* Wkl   = Wkh + WN;
    __bf16* Wvh   = Wkl + WN;
    __bf16* Woh   = Wvh + WN;
    __bf16* rfhb  = Woh + WN;              // RN
    __bf16* rflb  = rfhb + RN;             // RN
    float* Qnorm  = (float*)(rflb + RN);   // BT*16
    float* Knorm  = Qnorm + (size_t)BT * NHEAD;
    __bf16* KVthi = (__bf16*)(Knorm + (size_t)BT * NHEAD);  // KVTN
    __bf16* KVtlo = KVthi + KVTN;
    float* KVpart = (float*)Xhi;           // 4*KVTN fp32 = 21MB (dead after reduce)
    __bf16* Ybf   = Xhi;                   // overlays KVpart after reduce

    const dim3 blk(256);
    hipLaunchKernelGGL(split2_kernel, dim3(MN / 4 / 256), blk, 0, stream, x,  Xhi, Xlo, (int)(MN / 4));
    hipLaunchKernelGGL(split2_kernel, dim3(WN / 4 / 256), blk, 0, stream, wq, Wqh, Wql, (int)(WN / 4));
    hipLaunchKernelGGL(split2_kernel, dim3(WN / 4 / 256), blk, 0, stream, wk, Wkh, Wkl, (int)(WN / 4));
    hipLaunchKernelGGL(split1_kernel, dim3(WN / 4 / 256), blk, 0, stream, wv, Wvh, (int)(WN / 4));
    hipLaunchKernelGGL(split1_kernel, dim3(WN / 4 / 256), blk, 0, stream, wo, Woh, (int)(WN / 4));
    hipLaunchKernelGGL(split2_kernel, dim3(RN / 4 / 256), blk, 0, stream, rf, rfhb, rflb, (int)(RN / 4));

    const dim3 ggrid(DM / 128, BT / 128);
    hipLaunchKernelGGL((gemm_mfma_kernel<true, 2>), ggrid, blk, 0, stream,
                       Xhi, Xlo, Wqh, Wql, (float*)nullptr, Qb, Qnorm);
    hipLaunchKernelGGL((gemm_mfma_kernel<true, 2>), ggrid, blk, 0, stream,
                       Xhi, Xlo, Wkh, Wkl, (float*)nullptr, Kbf, Knorm);
    hipLaunchKernelGGL((gemm_mfma_kernel<false, 3>), ggrid, blk, 0, stream,
                       Xhi, (const __bf16*)nullptr, Wvh, (const __bf16*)nullptr,
                       (float*)nullptr, Vtb, (float*)nullptr);

    hipLaunchKernelGGL(kv_mfma_kernel, dim3(4, 32, 4), blk, 0, stream,
                       Kbf, Vtb, Knorm, rfhb, rflb, KVpart);
    hipLaunchKernelGGL(reduce_kv_kernel, dim3(KVTN / 4 / 256), blk, 0, stream,
                       KVpart, KVthi, KVtlo);
    hipLaunchKernelGGL(qkv_mfma_kernel, dim3(32, 32), blk, 0, stream,
                       Qb, Qnorm, rfhb, rflb, KVthi, KVtlo, Ybf);

    hipLaunchKernelGGL((gemm_mfma_kernel<false, 0>), ggrid, blk, 0, stream,
                       Ybf, (const __bf16*)nullptr, Woh, (const __bf16*)nullptr,
                       out, (__bf16*)nullptr, (float*)nullptr);
}

// Round 4
// 358.923 us; speedup vs baseline: 4.3846x; 1.1529x over previous
//
#include <hip/hip_runtime.h>

// PerformerAttention: B=2, T=4096, D=1024, H=16, Dh=64, m=256, 2m=512.
// R4: XOR chunk-swizzle (16B granularity, chunk ^= (row>>1)&3) on all staged
// LDS tiles + MFMA fragment reads -> <=2-way bank conflicts (free). kv: phi
// single-bf16, D[v][f] operand order (coalesced KVpart), 50KB LDS -> 3
// blocks/CU, z=8. qkv: KVt single-bf16, 45KB LDS -> 3 blocks/CU.
// Precision kept: x,wq,wk,rf split hi/lo (3-product GEMMs for Q/K).

#define TSEQ  4096
#define BSZ   2
#define BT    8192
#define DM    1024
#define NHEAD 16
#define DHEAD 64
#define FF    512   // 2m

typedef __attribute__((ext_vector_type(8))) __bf16 bf16x8;
typedef __attribute__((ext_vector_type(4))) __bf16 bf16x4;
typedef __attribute__((ext_vector_type(4))) float floatx4;

#define MFMA_BF16(a, b, c) __builtin_amdgcn_mfma_f32_16x16x32_bf16(a, b, c, 0, 0, 0)

__device__ __forceinline__ void load_lds_16B(const void* g, void* l) {
    __builtin_amdgcn_global_load_lds(
        (const __attribute__((address_space(1))) void*)g,
        (__attribute__((address_space(3))) void*)l, 16, 0, 0);
}

// ---------------------------------------------------------------------------
__global__ __launch_bounds__(256) void split2_kernel(
    const float* __restrict__ src, __bf16* __restrict__ hi, __bf16* __restrict__ lo, int n4)
{
    int i = blockIdx.x * 256 + threadIdx.x;
    if (i >= n4) return;
    float4 v = ((const float4*)src)[i];
    bf16x4 h = {(__bf16)v.x, (__bf16)v.y, (__bf16)v.z, (__bf16)v.w};
    bf16x4 l = {(__bf16)(v.x - (float)h[0]), (__bf16)(v.y - (float)h[1]),
                (__bf16)(v.z - (float)h[2]), (__bf16)(v.w - (float)h[3])};
    ((bf16x4*)hi)[i] = h;
    ((bf16x4*)lo)[i] = l;
}

__global__ __launch_bounds__(256) void split1_kernel(
    const float* __restrict__ src, __bf16* __restrict__ hi, int n4)
{
    int i = blockIdx.x * 256 + threadIdx.x;
    if (i >= n4) return;
    float4 v = ((const float4*)src)[i];
    bf16x4 h = {(__bf16)v.x, (__bf16)v.y, (__bf16)v.z, (__bf16)v.w};
    ((bf16x4*)hi)[i] = h;
}

// ---------------------------------------------------------------------------
// bf16 MFMA GEMM: C[8192,1024] = A @ W^T. SPLIT: 3-product hi/lo.
// EPI: 0 fp32 C; 1 bf16 C; 2 bf16 C + per-head row norms ([h][BT] layout);
// 3 transposed-bf16 (Vt [bh][64 v][4096 t]).
// LDS tiles chunk-xor-swizzled: slot (row, c) holds global chunk c^((row>>1)&3).
template<bool SPLIT, int EPI>
__global__ __launch_bounds__(256, 2)
void gemm_mfma_kernel(const __bf16* __restrict__ Ahi, const __bf16* __restrict__ Alo,
                      const __bf16* __restrict__ Whi, const __bf16* __restrict__ Wlo,
                      float* __restrict__ Cf, __bf16* __restrict__ Cb,
                      float* __restrict__ norms)
{
    __shared__ __bf16 As[SPLIT ? 2 : 1][128 * 32];
    __shared__ __bf16 Bs[SPLIT ? 2 : 1][128 * 32];

    const int t = threadIdx.x;
    const int bm = blockIdx.y * 128, bn = blockIdx.x * 128;
    const int lane = t & 63, mth = lane & 15, q = lane >> 4, wave = t >> 6;
    const int wrow = (wave & 1) * 64, wcol = (wave >> 1) * 64;
    const int qsw = q ^ ((mth >> 1) & 3);              // fragment chunk swizzle
    const int csw = (t & 3) ^ ((t >> 3) & 3);          // staging chunk swizzle

    const size_t arow = (size_t)(bm + (t >> 2)) * DM + csw * 8;
    const size_t brow = (size_t)(bn + (t >> 2)) * DM + csw * 8;
    const int l0 = t * 8;
    const int l1 = 64 * 32 + t * 8;

    floatx4 acc[4][4];
#pragma unroll
    for (int i = 0; i < 4; ++i)
#pragma unroll
        for (int j = 0; j < 4; ++j) acc[i][j] = (floatx4){0.f, 0.f, 0.f, 0.f};

    for (int k0 = 0; k0 < DM; k0 += 32) {
        __syncthreads();
        load_lds_16B(Ahi + arow + k0,             &As[0][l0]);
        load_lds_16B(Ahi + arow + 64 * DM + k0,   &As[0][l1]);
        load_lds_16B(Whi + brow + k0,             &Bs[0][l0]);
        load_lds_16B(Whi + brow + 64 * DM + k0,   &Bs[0][l1]);
        if (SPLIT) {
            load_lds_16B(Alo + arow + k0,           &As[1][l0]);
            load_lds_16B(Alo + arow + 64 * DM + k0, &As[1][l1]);
            load_lds_16B(Wlo + brow + k0,           &Bs[1][l0]);
            load_lds_16B(Wlo + brow + 64 * DM + k0, &Bs[1][l1]);
        }
        __syncthreads();

        bf16x8 ah[4], bh[4], al[4], bl[4];
#pragma unroll
        for (int i = 0; i < 4; ++i) {
            ah[i] = *(const bf16x8*)&As[0][(wrow + i * 16 + mth) * 32 + qsw * 8];
            bh[i] = *(const bf16x8*)&Bs[0][(wcol + i * 16 + mth) * 32 + qsw * 8];
        }
        if (SPLIT) {
#pragma unroll
            for (int i = 0; i < 4; ++i) {
                al[i] = *(const bf16x8*)&As[1][(wrow + i * 16 + mth) * 32 + qsw * 8];
                bl[i] = *(const bf16x8*)&Bs[1][(wcol + i * 16 + mth) * 32 + qsw * 8];
            }
        }
#pragma unroll
        for (int i = 0; i < 4; ++i)
#pragma unroll
            for (int j = 0; j < 4; ++j) {
                acc[i][j] = MFMA_BF16(ah[i], bh[j], acc[i][j]);
                if (SPLIT) {
                    acc[i][j] = MFMA_BF16(ah[i], bl[j], acc[i][j]);
                    acc[i][j] = MFMA_BF16(al[i], bh[j], acc[i][j]);
                }
            }
    }

    if (EPI == 2) {
        const int head = (bn + wcol) >> 6;   // wave's 64 cols = exactly 1 head
#pragma unroll
        for (int i = 0; i < 4; ++i)
#pragma unroll
            for (int r = 0; r < 4; ++r) {
                float s = acc[i][0][r] * acc[i][0][r] + acc[i][1][r] * acc[i][1][r]
                        + acc[i][2][r] * acc[i][2][r] + acc[i][3][r] * acc[i][3][r];
                s += __shfl_xor(s, 1); s += __shfl_xor(s, 2);
                s += __shfl_xor(s, 4); s += __shfl_xor(s, 8);
                if (mth == 0)
                    norms[(size_t)head * BT + (bm + wrow + i * 16 + q * 4 + r)] = s;
            }
    }
    if (EPI == 3) {
#pragma unroll
        for (int i = 0; i < 4; ++i)
#pragma unroll
            for (int j = 0; j < 4; ++j) {
                const int cg = bn + wcol + j * 16 + mth;
                const int hh = cg >> 6, vloc = cg & 63;
                const int r0 = bm + wrow + i * 16 + q * 4;
                const int bb = r0 >> 12, tloc = r0 & 4095;
                bf16x4 w = {(__bf16)acc[i][j][0], (__bf16)acc[i][j][1],
                            (__bf16)acc[i][j][2], (__bf16)acc[i][j][3]};
                *(bf16x4*)(Cb + ((size_t)(bb * 16 + hh) * 64 + vloc) * TSEQ + tloc) = w;
            }
        return;
    }
#pragma unroll
    for (int i = 0; i < 4; ++i)
#pragma unroll
        for (int r = 0; r < 4; ++r) {
            const size_t gr = (size_t)(bm + wrow + i * 16 + q * 4 + r) * DM
                            + bn + wcol + mth;
            if (EPI == 0) {
#pragma unroll
                for (int j = 0; j < 4; ++j) Cf[gr + j * 16] = acc[i][j][r];
            } else {
#pragma unroll
                for (int j = 0; j < 4; ++j) Cb[gr + j * 16] = (__bf16)acc[i][j][r];
            }
        }
}

// ---------------------------------------------------------------------------
// kv: grid (4 fb, 32 bh, 8 z), 8 chunks of 64 t each. Per chunk:
// proj[t][f] = K.rf (split rf) -> phi (single bf16, pages [kt][128 f][64B t])
// -> KV[v][f] += Vt.phi (D rows = v -> coalesced f-major KVpart writes).
// Vt ones-rows v=64..79 give Ksum in row 64. LDS 50.3KB -> 3 blocks/CU.
__global__ __launch_bounds__(256, 3)
void kv_mfma_kernel(const __bf16* __restrict__ Kb, const __bf16* __restrict__ Vt,
                    const float* __restrict__ Knorm,
                    const __bf16* __restrict__ rfh_g, const __bf16* __restrict__ rfl_g,
                    float* __restrict__ KVpart)
{
    __shared__ __bf16 rfh[4096], rfl[4096], Kc[4096], VtS[5120], phiT[8192];
    __shared__ float scaleS[64];

    const int fb = blockIdx.x, bh = blockIdx.y, z = blockIdx.z;
    const int b = bh >> 4, h = bh & 15;
    const int tid = threadIdx.x, wave = tid >> 6, lane = tid & 63;
    const int m = lane & 15, q = lane >> 4;
    const int lr = lane >> 2;
    const int csw = (lane & 3) ^ ((lr >> 1) & 3);
    const int qsw = q ^ ((m >> 1) & 3);

#pragma unroll
    for (int L = 0; L < 2; ++L) {
        const int f = wave * 16 + lr, d = L * 32 + csw * 8;
        load_lds_16B(rfh_g + (size_t)(fb * 64 + f) * DHEAD + d,
                     (char*)rfh + L * 4096 + wave * 1024 + lane * 16);
        load_lds_16B(rfl_g + (size_t)(fb * 64 + f) * DHEAD + d,
                     (char*)rfl + L * 4096 + wave * 1024 + lane * 16);
    }
    for (int idx = tid; idx < 1024; idx += 256) {     // ones rows (row-constant)
        const int kt = idx >> 9, rr = (idx >> 5) & 15, cc = idx & 31;
        VtS[kt * 2560 + (64 + rr) * 32 + cc] = (rr == 0) ? (__bf16)1.0f : (__bf16)0.0f;
    }

    floatx4 acc[2][5];
#pragma unroll
    for (int s = 0; s < 2; ++s)
#pragma unroll
        for (int v = 0; v < 5; ++v) acc[s][v] = (floatx4){0.f, 0.f, 0.f, 0.f};

    for (int ch = z * 8; ch < z * 8 + 8; ++ch) {
        __syncthreads();   // prev chunk done reading Kc/VtS/phiT
#pragma unroll
        for (int L = 0; L < 2; ++L) {
            const int tr = wave * 16 + lr, d = L * 32 + csw * 8;
            load_lds_16B(Kb + (size_t)(b * TSEQ + ch * 64 + tr) * DM + h * 64 + d,
                         (char*)Kc + L * 4096 + wave * 1024 + lane * 16);
            load_lds_16B(Vt + ((size_t)bh * 64 + tr) * TSEQ + ch * 64 + d,
                         (char*)VtS + L * 5120 + wave * 1024 + lane * 16);
        }
        if (tid < 64)
            scaleS[tid] = __expf(-0.5f * Knorm[(size_t)h * BT + b * TSEQ + ch * 64 + tid]) * 0.0625f;
        __syncthreads();

        // proj[t][f]: X = K rows (wave t-strip), Y = rf rows
        floatx4 pr[4];
#pragma unroll
        for (int ft = 0; ft < 4; ++ft) pr[ft] = (floatx4){0.f, 0.f, 0.f, 0.f};
#pragma unroll
        for (int kt = 0; kt < 2; ++kt) {
            const bf16x8 ka = *(const bf16x8*)(Kc + kt * 2048 + (wave * 16 + m) * 32 + qsw * 8);
#pragma unroll
            for (int ft = 0; ft < 4; ++ft) {
                const bf16x8 yh = *(const bf16x8*)(rfh + kt * 2048 + (ft * 16 + m) * 32 + qsw * 8);
                const bf16x8 yl = *(const bf16x8*)(rfl + kt * 2048 + (ft * 16 + m) * 32 + qsw * 8);
                pr[ft] = MFMA_BF16(ka, yh, pr[ft]);
                pr[ft] = MFMA_BF16(ka, yl, pr[ft]);
            }
        }
        // phi write: lane holds t = wave*16+q*4+r at f = ft*16+m
        {
            const int pg = wave >> 1;                 // t-half page
            const int cph = (wave & 1) * 2 + (q >> 1);
            const int sub8 = (q & 1) * 8;
#pragma unroll
            for (int ft = 0; ft < 4; ++ft) {
                const int fo = ft * 16 + m;
                bf16x4 pc, ps;
#pragma unroll
                for (int r = 0; r < 4; ++r) {
                    const float sc = scaleS[wave * 16 + q * 4 + r];
                    float sv, cv;
                    __sincosf(pr[ft][r], &sv, &cv);
                    pc[r] = (__bf16)(cv * sc);
                    ps[r] = (__bf16)(sv * sc);
                }
                const int off = pg * 8192 + fo * 64 + (cph ^ ((m >> 1) & 3)) * 16 + sub8;
                *(bf16x4*)((char*)phiT + off) = pc;
                *(bf16x4*)((char*)phiT + off + 4096) = ps;   // sin rows fo+64
            }
        }
        __syncthreads();

        // KV[v][f]: X = Vt rows, Y = phi rows (wave's 32-f slice)
#pragma unroll
        for (int kt = 0; kt < 2; ++kt) {
            bf16x8 yph[2];
#pragma unroll
            for (int f2 = 0; f2 < 2; ++f2)
                yph[f2] = *(const bf16x8*)((char*)phiT + kt * 8192
                          + (wave * 32 + f2 * 16 + m) * 64 + qsw * 16);
#pragma unroll
            for (int vt = 0; vt < 5; ++vt) {
                const bf16x8 xv = *(const bf16x8*)(VtS + kt * 2560 + (vt * 16 + m) * 32 + qsw * 8);
#pragma unroll
                for (int f2 = 0; f2 < 2; ++f2)
                    acc[f2][vt] = MFMA_BF16(xv, yph[f2], acc[f2][vt]);
            }
        }
    }

    // KVpart[z][bh][80 v][512 f], coalesced along f (col = m)
#pragma unroll
    for (int f2 = 0; f2 < 2; ++f2) {
        const int fo = wave * 32 + f2 * 16 + m;
        const int fg = (fo < 64) ? fb * 64 + fo : 256 + fb * 64 + (fo - 64);
#pragma unroll
        for (int vt = 0; vt < 5; ++vt) {
            float* base = KVpart + ((size_t)(z * 32 + bh) * 80 + vt * 16 + q * 4) * 512 + fg;
#pragma unroll
            for (int r = 0; r < 4; ++r) base[(size_t)r * 512] = acc[f2][vt][r];
        }
    }
}

#define KVTN (32 * 80 * 512)   // 1310720

__global__ __launch_bounds__(256) void reduce_kv_kernel(
    const float* __restrict__ KVpart, __bf16* __restrict__ KVthi)
{
    const int i = blockIdx.x * 256 + threadIdx.x;   // float4 index < KVTN/4
    const float4* P = (const float4*)KVpart;
    float4 s = P[i];
#pragma unroll
    for (int j = 1; j < 8; ++j) {
        const float4 p = P[i + (size_t)j * (KVTN / 4)];
        s.x += p.x; s.y += p.y; s.z += p.z; s.w += p.w;
    }
    bf16x4 hv = {(__bf16)s.x, (__bf16)s.y, (__bf16)s.z, (__bf16)s.w};
    ((bf16x4*)KVthi)[i] = hv;
}

// ---------------------------------------------------------------------------
// qkv: grid (32 tt, 32 bh), t-tile 128 (2 subs of 64). Per fb: stage KVt
// slice (bf16, hi only); per sub: projT[f][t] = rf.Q (split rf) -> phi
// (pages [4 ktf][64 t][64B f]) -> OT[v][t] += KVt.phi. Z = OT row v=64.
// LDS 44.5KB -> 3 blocks/CU.
__global__ __launch_bounds__(256, 3)
void qkv_mfma_kernel(const __bf16* __restrict__ Qb, const float* __restrict__ Qnorm,
                     const __bf16* __restrict__ rfh_g, const __bf16* __restrict__ rfl_g,
                     const __bf16* __restrict__ KVthi, __bf16* __restrict__ Ybf)
{
    __shared__ __bf16 Qs[4096], uS[8192], KVh[10240];
    __shared__ float scaleS[128];

    const int tt = blockIdx.x, bh = blockIdx.y;
    const int b = bh >> 4, h = bh & 15;
    const int t0 = tt * 128;
    const int tid = threadIdx.x, wave = tid >> 6, lane = tid & 63;
    const int m = lane & 15, q = lane >> 4;
    const int lr = lane >> 2;
    const int csw = (lane & 3) ^ ((lr >> 1) & 3);
    const int qsw = q ^ ((m >> 1) & 3);

    if (tid < 128)
        scaleS[tid] = __expf(-0.5f * Qnorm[(size_t)h * BT + b * TSEQ + t0 + tid]) * 0.0625f;

    floatx4 acc[2][5];
#pragma unroll
    for (int s = 0; s < 2; ++s)
#pragma unroll
        for (int v = 0; v < 5; ++v) acc[s][v] = (floatx4){0.f, 0.f, 0.f, 0.f};

    for (int fb = 0; fb < 4; ++fb) {
        __syncthreads();   // prev fb's OT done with KVh
        {   // stage KVt slice: pages [4 ktf][80 v][64B f']; wave = ktf page
            const int fgb = (wave < 2) ? fb * 64 + wave * 32 : 256 + fb * 64 + (wave - 2) * 32;
#pragma unroll
            for (int L = 0; L < 5; ++L) {
                const int v = L * 16 + lr;
                load_lds_16B(KVthi + ((size_t)bh * 80 + v) * 512 + fgb + csw * 8,
                             (char*)KVh + wave * 5120 + L * 1024 + lane * 16);
            }
        }
        for (int sub = 0; sub < 2; ++sub) {
            __syncthreads();   // prev sub done with Qs/uS (also covers KVh stage)
#pragma unroll
            for (int L = 0; L < 2; ++L) {
                const int tr = wave * 16 + lr, d = L * 32 + csw * 8;
                load_lds_16B(Qb + (size_t)(b * TSEQ + t0 + sub * 64 + tr) * DM + h * 64 + d,
                             (char*)Qs + L * 4096 + wave * 1024 + lane * 16);
                load_lds_16B(rfh_g + (size_t)(fb * 64 + tr) * DHEAD + d,
                             (char*)uS + L * 4096 + wave * 1024 + lane * 16);
                load_lds_16B(rfl_g + (size_t)(fb * 64 + tr) * DHEAD + d,
                             (char*)uS + 8192 + L * 4096 + wave * 1024 + lane * 16);
            }
            __syncthreads();

            // projT[f][t]: X = rf rows (wave f-strip), Y = Q rows (t-tiles)
            floatx4 pr[4];
#pragma unroll
            for (int i = 0; i < 4; ++i) pr[i] = (floatx4){0.f, 0.f, 0.f, 0.f};
#pragma unroll
            for (int kt = 0; kt < 2; ++kt) {
                const bf16x8 xh = *(const bf16x8*)(uS + kt * 2048 + (wave * 16 + m) * 32 + qsw * 8);
                const bf16x8 xl = *(const bf16x8*)(uS + 4096 + kt * 2048 + (wave * 16 + m) * 32 + qsw * 8);
#pragma unroll
                for (int tt_ = 0; tt_ < 4; ++tt_) {
                    const bf16x8 yq = *(const bf16x8*)(Qs + kt * 2048 + (tt_ * 16 + m) * 32 + qsw * 8);
                    pr[tt_] = MFMA_BF16(xh, yq, pr[tt_]);
                    pr[tt_] = MFMA_BF16(xl, yq, pr[tt_]);
                }
            }
            __syncthreads();   // proj reads of uS done -> phi overwrites uS

            // phi write: lane holds f = wave*16+q*4+r at t = tt_*16+m
            {
                const int pg = wave >> 1;              // cos f-half page
                const int cph = (wave & 1) * 2 + (q >> 1);
                const int sub8 = (q & 1) * 8;
#pragma unroll
                for (int tt_ = 0; tt_ < 4; ++tt_) {
                    const int tloc = tt_ * 16 + m;
                    const float sc = scaleS[sub * 64 + tloc];
                    bf16x4 pc, ps;
#pragma unroll
                    for (int r = 0; r < 4; ++r) {
                        float sv, cv;
                        __sincosf(pr[tt_][r], &sv, &cv);
                        pc[r] = (__bf16)(cv * sc);
                        ps[r] = (__bf16)(sv * sc);
                    }
                    const int off = pg * 4096 + tloc * 64 + (cph ^ ((m >> 1) & 3)) * 16 + sub8;
                    *(bf16x4*)((char*)uS + off) = pc;          // cos: pages 0,1
                    *(bf16x4*)((char*)uS + off + 8192) = ps;   // sin: pages 2,3
                }
            }
            __syncthreads();

            // OT[v][t]: X = KVt rows, Y = phi rows (wave t-slice)
#pragma unroll
            for (int ktf = 0; ktf < 4; ++ktf) {
                const bf16x8 yf = *(const bf16x8*)((char*)uS + ktf * 4096
                                  + (wave * 16 + m) * 64 + qsw * 16);
#pragma unroll
                for (int vt = 0; vt < 5; ++vt) {
                    const bf16x8 xh = *(const bf16x8*)(KVh + ktf * 2560 + (vt * 16 + m) * 32 + qsw * 8);
                    acc[sub][vt] = MFMA_BF16(xh, yf, acc[sub][vt]);
                }
            }
        }
    }
    // epilogue: Z at (v=64) = vt 4, q 0, reg 0, col t = m
#pragma unroll
    for (int sub = 0; sub < 2; ++sub) {
        const float zv = __shfl(acc[sub][4][0], m);
        const float inv = 1.0f / fmaxf(zv, 1e-6f);
        const size_t tg = (size_t)(b * TSEQ + t0 + sub * 64 + wave * 16 + m);
#pragma unroll
        for (int vt = 0; vt < 4; ++vt) {
            bf16x4 w;
#pragma unroll
            for (int r = 0; r < 4; ++r) w[r] = (__bf16)(acc[sub][vt][r] * inv);
            *(bf16x4*)(Ybf + tg * DM + h * 64 + vt * 16 + q * 4) = w;
        }
    }
}

// ---------------------------------------------------------------------------
extern "C" void kernel_launch(void* const* d_in, const int* in_sizes, int n_in,
                              void* d_out, int out_size, void* d_ws, size_t ws_size,
                              hipStream_t stream)
{
    (void)in_sizes; (void)n_in; (void)out_size; (void)ws_size;
    const float* x  = (const float*)d_in[0];
    const float* wq = (const float*)d_in[1];
    const float* wk = (const float*)d_in[2];
    const float* wv = (const float*)d_in[3];
    const float* wo = (const float*)d_in[4];
    const float* rf = (const float*)d_in[5];
    float* out = (float*)d_out;

    const size_t MN = (size_t)BT * DM;     // 8388608
    const size_t WN = (size_t)DM * DM;     // 1048576
    const size_t RN = 256 * 64;            // 16384

    __bf16* Qb    = (__bf16*)d_ws;         // MN
    __bf16* Kbf   = Qb   + MN;             // MN
    __bf16* Vtb   = Kbf  + MN;             // MN  ([bh][64 v][4096 t])
    __bf16* Xhi   = Vtb  + MN;             // MN
    __bf16* Xlo   = Xhi  + MN;             // MN
    __bf16* Wqh   = Xlo  + MN;             // WN each
    __bf16* Wql   = Wqh + WN;
    __bf16* Wkh   = Wql + WN;
    __bf16* Wkl   = Wkh + WN;
    __bf16* Wvh   = Wkl + WN;
    __bf16* Woh   = Wvh + WN;
    __bf16* rfhb  = Woh + WN;              // RN
    __bf16* rflb  = rfhb + RN;             // RN
    float* Qnorm  = (float*)(rflb + RN);   // [16 h][BT]
    float* Knorm  = Qnorm + (size_t)BT * NHEAD;
    __bf16* KVthi = (__bf16*)(Knorm + (size_t)BT * NHEAD);  // KVTN
    // KVpart (8*KVTN fp32 = 41.9MB) overlays Xhi..Wvh (42MB, dead by then)
    float* KVpart = (float*)Xhi;
    __bf16* Ybf   = Xhi;                   // after reduce, qkv output

    const dim3 blk(256);
    hipLaunchKernelGGL(split2_kernel, dim3(MN / 4 / 256), blk, 0, stream, x,  Xhi, Xlo, (int)(MN / 4));
    hipLaunchKernelGGL(split2_kernel, dim3(WN / 4 / 256), blk, 0, stream, wq, Wqh, Wql, (int)(WN / 4));
    hipLaunchKernelGGL(split2_kernel, dim3(WN / 4 / 256), blk, 0, stream, wk, Wkh, Wkl, (int)(WN / 4));
    hipLaunchKernelGGL(split1_kernel, dim3(WN / 4 / 256), blk, 0, stream, wv, Wvh, (int)(WN / 4));
    hipLaunchKernelGGL(split1_kernel, dim3(WN / 4 / 256), blk, 0, stream, wo, Woh, (int)(WN / 4));
    hipLaunchKernelGGL(split2_kernel, dim3(RN / 4 / 256), blk, 0, stream, rf, rfhb, rflb, (int)(RN / 4));

    const dim3 ggrid(DM / 128, BT / 128);  // (8, 64)
    hipLaunchKernelGGL((gemm_mfma_kernel<true, 2>), ggrid, blk, 0, stream,
                       Xhi, Xlo, Wqh, Wql, (float*)nullptr, Qb, Qnorm);
    hipLaunchKernelGGL((gemm_mfma_kernel<true, 2>), ggrid, blk, 0, stream,
                       Xhi, Xlo, Wkh, Wkl, (float*)nullptr, Kbf, Knorm);
    hipLaunchKernelGGL((gemm_mfma_kernel<false, 3>), ggrid, blk, 0, stream,
                       Xhi, (const __bf16*)nullptr, Wvh, (const __bf16*)nullptr,
                       (float*)nullptr, Vtb, (float*)nullptr);

    hipLaunchKernelGGL(kv_mfma_kernel, dim3(4, 32, 8), blk, 0, stream,
                       Kbf, Vtb, Knorm, rfhb, rflb, KVpart);
    hipLaunchKernelGGL(reduce_kv_kernel, dim3(KVTN / 4 / 256), blk, 0, stream,
                       KVpart, KVthi);
    hipLaunchKernelGGL(qkv_mfma_kernel, dim3(32, 32), blk, 0, stream,
                       Qb, Qnorm, rfhb, rflb, KVthi, Ybf);

    hipLaunchKernelGGL((gemm_mfma_kernel<false, 0>), ggrid, blk, 0, stream,
                       Ybf, (const __bf16*)nullptr, Woh, (const __bf16*)nullptr,
                       out, (__bf16*)nullptr, (float*)nullptr);
}